// Round 16
// baseline (3396.441 us; speedup 1.0000x reference)
//
#include <hip/hip_runtime.h>
#include <hip/hip_fp16.h>
#include <hip/hip_cooperative_groups.h>
#include <math.h>
#include <stdint.h>

#define DIM 10
#define NTILE 256
#define BKT_LOG 8
#define BKT 256                   // nodes per bucket == threads per WG
#define NBMAX 2048
#define EPW 2048                  // edges per WG in binning
#define KPT (EPW / 256)
#define NPART 8                   // send partitions (s>>16: 64K nodes = 2MB h16)
#define PSHIFT 16
#define CAP 448                   // slots per (p,b) cell: mean 288 + 9.4 sigma
#define OVFCAP 32768
#define D2WORDS 32768
#define XSTR 11                   // xl LDS stride (coprime with 32 banks)

// meta (u32): cnt[NPART*NBMAX] | ovfc[8] | ovf[OVFCAP] | depth2[D2WORDS]
// ws: h16a[n*16 u16] | h16b[n*16 u16] | bins[NPART*NB*CAP u32] | meta

struct GruW {
    const float *Wz, *bz, *Uz, *buz, *Wr, *br, *Ur, *bur, *Wh, *bh, *Uh, *buh;
};

__device__ __forceinline__ float2 cvt2(uint32_t u) {
    __half2 hh = *reinterpret_cast<__half2*>(&u);
    return __half22float2(hh);
}

__device__ __forceinline__ int d2get(const uint32_t* __restrict__ depth2, int node) {
    uint32_t w = depth2[(uint32_t)node >> 4];
    return (int)((w >> ((node & 15) * 2)) & 3u);
}

// ---------------------------------------------------------------------------
// prep: [0,pack) pack depth->2b | rest zero cell counters + ovfc
// ---------------------------------------------------------------------------
__global__ void prep_kernel(const int* __restrict__ depth,
                            uint32_t* __restrict__ depth2,
                            uint32_t* __restrict__ cnts,
                            int n, int pack_blocks, int cnt_tot)
{
    __shared__ int sd[4096];
    const int t = threadIdx.x;
    const int bid = blockIdx.x;
    if (bid < pack_blocks) {
        const int base = bid * 4096;
        for (int i = t; i < 4096; i += 256) {
            int g = base + i;
            sd[i] = (g < n) ? depth[g] : 3;
        }
        __syncthreads();
        int wb = (base >> 4) + t;
        if (wb * 16 < n) {
            uint32_t v = 0;
            #pragma unroll
            for (int j = 0; j < 16; ++j)
                v |= ((uint32_t)(sd[t * 16 + j] & 3)) << (2 * j);
            depth2[wb] = v;
        }
    } else {
        int i = (bid - pack_blocks) * 256 + t;
        if (i < cnt_tot) cnts[i] = 0;
    }
}

// ---------------------------------------------------------------------------
// binit: blocks [0,bin_blocks) bin edges into (p,b) cells; rest init h16a.
// word = s(19b) | rl(8b)<<19 | flag(useful@iter1)<<27
// ---------------------------------------------------------------------------
__global__ __launch_bounds__(256) void binit_kernel(
                           const int* __restrict__ recv,
                           const int* __restrict__ send,
                           const uint32_t* __restrict__ depth2,
                           const int* __restrict__ depth,
                           const float* __restrict__ h_in,
                           uint16_t* __restrict__ h16a,
                           uint32_t* __restrict__ cnt,
                           uint32_t* __restrict__ ovfc,
                           uint32_t* __restrict__ ovf,
                           uint32_t* __restrict__ bins,
                           int ne, int n, int NB, int bin_blocks)
{
    __shared__ float sh[NTILE * 11];
    const int t = threadIdx.x;
    const int bid = blockIdx.x;

    if (bid < bin_blocks) {
        const int base = bid * EPW;
        int rA[KPT], sA[KPT];
        #pragma unroll
        for (int k = 0; k < KPT; ++k) {
            int e = base + k * 256 + t;
            if (e < ne) { rA[k] = recv[e]; sA[k] = send[e]; }
            else        { rA[k] = -1;      sA[k] = 0;       }
        }
        int drA[KPT], dsA[KPT];
        #pragma unroll
        for (int k = 0; k < KPT; ++k) {
            if (rA[k] >= 0) { drA[k] = d2get(depth2, rA[k]); dsA[k] = d2get(depth2, sA[k]); }
            else            { drA[k] = 3;                    dsA[k] = 3;                    }
        }
        #pragma unroll
        for (int k = 0; k < KPT; ++k) {
            if (rA[k] >= 0 && drA[k] <= 2 && dsA[k] <= 2) {
                int r = rA[k], s = sA[k];
                bool f1 = (drA[k] <= 1) && (dsA[k] <= 1);
                uint32_t w = (uint32_t)s | ((uint32_t)(r & (BKT - 1)) << 19)
                           | (f1 ? (1u << 27) : 0u);
                int cell = (s >> PSHIFT) * NB + (r >> BKT_LOG);
                uint32_t pos = atomicAdd(&cnt[cell], 1u);
                if (pos < CAP) bins[(size_t)cell * CAP + pos] = w;
                else { uint32_t oi = atomicAdd(ovfc, 1u);
                       if (oi < OVFCAP) ovf[oi] = (uint32_t)(base + k * 256 + t); }
            }
        }
    } else {
        // init: h16a[node] = fp16( (depth<=2) ? h_in[node] : 0 ), pads 0
        const int base = (bid - bin_blocks) * NTILE;
        const long gbase = (long)base * DIM;
        const long glim  = (long)n * DIM;
        for (int idx = t; idx < NTILE * DIM; idx += NTILE) {
            long g = gbase + idx;
            float v = (g < glim) ? h_in[g] : 0.0f;
            sh[(idx / DIM) * 11 + (idx % DIM)] = v;
        }
        __syncthreads();
        const int node = base + t;
        if (node < n && depth[node] > 2) {
            #pragma unroll
            for (int c = 0; c < DIM; ++c) sh[t * 11 + c] = 0.0f;
        }
        __syncthreads();
        uint32_t* o16 = reinterpret_cast<uint32_t*>(h16a);
        const long o16base = (long)base * 8;
        const long o16lim  = (long)n * 8;
        for (int idx = t; idx < NTILE * 8; idx += NTILE) {
            long g = o16base + idx;
            if (g < o16lim) {
                int nl = idx / 8, c2 = idx % 8;
                uint32_t w = 0;
                if (c2 < 5) {
                    __half2 hh = __floats2half2_rn(sh[nl * 11 + 2 * c2],
                                                   sh[nl * 11 + 2 * c2 + 1]);
                    w = *reinterpret_cast<uint32_t*>(&hh);
                }
                o16[g] = w;
            }
        }
    }
}

// ---------------------------------------------------------------------------
// fused scatter + GRU, HARD partition phasing (COOP=1: grid.sync between
// partitions keeps all WGs gathering from the same 2MB h-slice -> per-XCD
// L2-resident gathers). COOP=0 fallback = round-15 soft version (correct,
// just slower). The sync is performance-only: each WG touches only its own
// LDS slice and its own cells; iteration boundary stays a launch boundary.
// ---------------------------------------------------------------------------
template<int ITER, int COOP>
__global__ __launch_bounds__(256, 8) void scatgru_kernel(
                            const uint32_t* __restrict__ bins,
                            const uint32_t* __restrict__ cnt,
                            const uint32_t* __restrict__ ovfc,
                            const uint32_t* __restrict__ ovf,
                            const int* __restrict__ recv,
                            const int* __restrict__ send,
                            const int* __restrict__ depth,
                            const uint16_t* __restrict__ hcur,  // stride 16 halfs
                            uint16_t* __restrict__ hnext,       // ITER==0 out
                            float* __restrict__ out32,          // ITER==1 out
                            int n, int NB, GruW w)
{
    __shared__ float xl[BKT * XSTR];     // 11264 B
    __shared__ float sW[6][100];
    __shared__ float sb[3][10];

    const int t = threadIdx.x;
    if (t < 100) {
        sW[0][t] = w.Wz[t]; sW[1][t] = w.Uz[t];
        sW[2][t] = w.Wr[t]; sW[3][t] = w.Ur[t];
        sW[4][t] = w.Wh[t]; sW[5][t] = w.Uh[t];
    }
    if (t < 10) {
        sb[0][t] = w.bz[t] + w.buz[t];
        sb[1][t] = w.br[t] + w.bur[t];
        sb[2][t] = w.bh[t] + w.buh[t];
    }
    for (int i = t; i < BKT * XSTR; i += 256) xl[i] = 0.0f;
    __syncthreads();

    const int b = blockIdx.x;
    const int n0 = b << BKT_LOG;
    const int nb = min(BKT, n - n0);

    // phase 1: partition-phased gather + LDS accumulate
    for (int p = 0; p < NPART; ++p) {
        const int cell = p * NB + b;
        const size_t base = (size_t)cell * CAP;
        const int tot = (int)min(cnt[cell], (uint32_t)CAP);
        for (int i = t; i < tot; i += 256) {
            uint32_t ww = bins[base + i];
            if (ITER == 1 && !((ww >> 27) & 1u)) continue;
            size_t s = (size_t)(ww & 0x7FFFFu);
            uint4 q = *reinterpret_cast<const uint4*>(hcur + s * 16);
            uint32_t e8 = *reinterpret_cast<const uint32_t*>(hcur + s * 16 + 8);
            float2 f0 = cvt2(q.x), f1 = cvt2(q.y), f2 = cvt2(q.z), f3 = cvt2(q.w);
            float2 f4 = cvt2(e8);
            float* xr = xl + ((ww >> 19) & (BKT - 1)) * XSTR;
            atomicAdd(xr + 0, f0.x); atomicAdd(xr + 1, f0.y);
            atomicAdd(xr + 2, f1.x); atomicAdd(xr + 3, f1.y);
            atomicAdd(xr + 4, f2.x); atomicAdd(xr + 5, f2.y);
            atomicAdd(xr + 6, f3.x); atomicAdd(xr + 7, f3.y);
            atomicAdd(xr + 8, f4.x); atomicAdd(xr + 9, f4.y);
        }
        if (COOP && p + 1 < NPART) {
            cooperative_groups::this_grid().sync();   // perf-only lockstep
        }
    }

    // phase 2: rare overflow edges for this bucket
    {
        const uint32_t cntv = min(*ovfc, (uint32_t)OVFCAP);
        for (uint32_t i = t; i < cntv; i += 256) {
            int e = (int)ovf[i];
            int r = recv[e];
            if ((r >> BKT_LOG) != b) continue;
            int s = send[e];
            if (ITER == 1 && (depth[r] > 1 || depth[s] > 1)) continue;
            uint4 q = *reinterpret_cast<const uint4*>(hcur + (size_t)s * 16);
            uint32_t e8v = *reinterpret_cast<const uint32_t*>(hcur + (size_t)s * 16 + 8);
            float2 f0 = cvt2(q.x), f1 = cvt2(q.y), f2 = cvt2(q.z), f3 = cvt2(q.w);
            float2 f4 = cvt2(e8v);
            float* xr = xl + (r & (BKT - 1)) * XSTR;
            atomicAdd(xr + 0, f0.x); atomicAdd(xr + 1, f0.y);
            atomicAdd(xr + 2, f1.x); atomicAdd(xr + 3, f1.y);
            atomicAdd(xr + 4, f2.x); atomicAdd(xr + 5, f2.y);
            atomicAdd(xr + 6, f3.x); atomicAdd(xr + 7, f3.y);
            atomicAdd(xr + 8, f4.x); atomicAdd(xr + 9, f4.y);
        }
    }
    __syncthreads();

    // phase 3: GRU for node n0+t (register-dieted)
    if (t < nb) {
        const int node = n0 + t;
        const int dep = depth[node];
        const bool active = (dep + ITER) <= 2;

        float hv[DIM];
        {
            const uint16_t* hp = hcur + (size_t)node * 16;
            uint4 q = *reinterpret_cast<const uint4*>(hp);
            uint32_t e8v = *reinterpret_cast<const uint32_t*>(hp + 8);
            float2 f0 = cvt2(q.x), f1 = cvt2(q.y), f2 = cvt2(q.z), f3 = cvt2(q.w);
            float2 f4 = cvt2(e8v);
            hv[0] = f0.x; hv[1] = f0.y; hv[2] = f1.x; hv[3] = f1.y;
            hv[4] = f2.x; hv[5] = f2.y; hv[6] = f3.x; hv[7] = f3.y;
            hv[8] = f4.x; hv[9] = f4.y;
        }
        float xv[DIM];
        #pragma unroll
        for (int j = 0; j < DIM; ++j) xv[j] = xl[t * XSTR + j];

        float zz[DIM];
        if (active) {
            #pragma unroll
            for (int i = 0; i < DIM; ++i) {
                float az = sb[0][i];
                float ar = sb[1][i];
                #pragma unroll
                for (int j = 0; j < DIM; ++j) {
                    az = fmaf(xv[j], sW[0][i * DIM + j], az);
                    az = fmaf(hv[j], sW[1][i * DIM + j], az);
                    ar = fmaf(xv[j], sW[2][i * DIM + j], ar);
                    ar = fmaf(hv[j], sW[3][i * DIM + j], ar);
                }
                zz[i] = 1.0f / (1.0f + __expf(-az));
                xl[t * XSTR + i] = (1.0f / (1.0f + __expf(-ar))) * hv[i];  // rh
            }
        }

        if (ITER == 0) {
            uint32_t packed[5];
            float prev = 0.0f;
            #pragma unroll
            for (int i = 0; i < DIM; ++i) {
                float o;
                if (active) {
                    float ah = sb[2][i];
                    #pragma unroll
                    for (int j = 0; j < DIM; ++j) {
                        ah = fmaf(xv[j], sW[4][i * DIM + j], ah);
                        ah = fmaf(xl[t * XSTR + j], sW[5][i * DIM + j], ah);
                    }
                    o = zz[i] * hv[i] + (1.0f - zz[i]) * tanhf(ah);
                } else {
                    o = hv[i];
                }
                if (dep > 1) o = 0.0f;     // fold iter-1 mask
                if (i & 1) {
                    __half2 hh = __floats2half2_rn(prev, o);
                    packed[i >> 1] = *reinterpret_cast<uint32_t*>(&hh);
                } else prev = o;
            }
            uint4 o0 = make_uint4(packed[0], packed[1], packed[2], packed[3]);
            uint4 o1 = make_uint4(packed[4], 0u, 0u, 0u);
            *reinterpret_cast<uint4*>(hnext + (size_t)node * 16)     = o0;
            *reinterpret_cast<uint4*>(hnext + (size_t)node * 16 + 8) = o1;
        } else {
            float2* op = reinterpret_cast<float2*>(out32 + (size_t)node * DIM);
            float prev = 0.0f;
            #pragma unroll
            for (int i = 0; i < DIM; ++i) {
                float o;
                if (active) {
                    float ah = sb[2][i];
                    #pragma unroll
                    for (int j = 0; j < DIM; ++j) {
                        ah = fmaf(xv[j], sW[4][i * DIM + j], ah);
                        ah = fmaf(xl[t * XSTR + j], sW[5][i * DIM + j], ah);
                    }
                    o = zz[i] * hv[i] + (1.0f - zz[i]) * tanhf(ah);
                } else {
                    o = hv[i];
                }
                if (i & 1) op[i >> 1] = make_float2(prev, o);
                else prev = o;
            }
        }
    }
}

// ---------------------------------------------------------------------------
// fallback path (ws too small / n too large): fp32 global-atomic pipeline
// ---------------------------------------------------------------------------
__global__ void init_mask32_kernel(const float* __restrict__ hsrc,
                                   float* __restrict__ hdst,
                                   const int* __restrict__ depth, int n)
{
    int node = blockIdx.x * blockDim.x + threadIdx.x;
    if (node >= n) return;
    bool act = depth[node] <= 2;
    const float* s = hsrc + (size_t)node * DIM;
    float* d = hdst + (size_t)node * DIM;
    #pragma unroll
    for (int c = 0; c < DIM; ++c) d[c] = act ? s[c] : 0.0f;
}

__global__ void simple_scatter_kernel(const int* __restrict__ recv,
                                      const int* __restrict__ send,
                                      const float* __restrict__ hm,
                                      float* __restrict__ x, int ne)
{
    const int tid = blockIdx.x * blockDim.x + threadIdx.x;
    const int e = tid / DIM;
    if (e >= ne) return;
    const int c = tid - e * DIM;
    const int s = send[e];
    const float v = hm[(size_t)s * DIM + c];
    if (v != 0.0f) {
        const int r = recv[e];
        unsafeAtomicAdd(x + (size_t)r * DIM + c, v);
    }
}

__global__ void zero_buf_kernel(float4* __restrict__ p, int tot4) {
    int i = blockIdx.x * blockDim.x + threadIdx.x;
    if (i < tot4) p[i] = make_float4(0.0f, 0.0f, 0.0f, 0.0f);
}

__global__ void gru32_kernel(const float* __restrict__ x,
                             const float* __restrict__ h,
                             float* __restrict__ out,
                             const int* __restrict__ depth, int iter, int n, GruW w)
{
    __shared__ float sW[6][100];
    __shared__ float sb[3][10];
    const int t = threadIdx.x;
    if (t < 100) {
        sW[0][t] = w.Wz[t]; sW[1][t] = w.Uz[t];
        sW[2][t] = w.Wr[t]; sW[3][t] = w.Ur[t];
        sW[4][t] = w.Wh[t]; sW[5][t] = w.Uh[t];
    }
    if (t < 10) {
        sb[0][t] = w.bz[t] + w.buz[t];
        sb[1][t] = w.br[t] + w.bur[t];
        sb[2][t] = w.bh[t] + w.buh[t];
    }
    __syncthreads();

    int node = blockIdx.x * blockDim.x + t;
    if (node >= n) return;
    const int dep = depth[node];
    const bool active = dep + iter <= 2;
    float xv[DIM], hv[DIM], outv[DIM];
    #pragma unroll
    for (int j = 0; j < DIM; ++j) {
        xv[j] = x[(size_t)node * DIM + j];
        hv[j] = h[(size_t)node * DIM + j];
    }
    if (active) {
        float zz[DIM], rh[DIM];
        #pragma unroll
        for (int i = 0; i < DIM; ++i) {
            float az = sb[0][i], ar = sb[1][i];
            #pragma unroll
            for (int j = 0; j < DIM; ++j) {
                az = fmaf(xv[j], sW[0][i * DIM + j], az);
                az = fmaf(hv[j], sW[1][i * DIM + j], az);
                ar = fmaf(xv[j], sW[2][i * DIM + j], ar);
                ar = fmaf(hv[j], sW[3][i * DIM + j], ar);
            }
            zz[i] = 1.0f / (1.0f + __expf(-az));
            rh[i] = (1.0f / (1.0f + __expf(-ar))) * hv[i];
        }
        #pragma unroll
        for (int i = 0; i < DIM; ++i) {
            float ah = sb[2][i];
            #pragma unroll
            for (int j = 0; j < DIM; ++j) {
                ah = fmaf(xv[j], sW[4][i * DIM + j], ah);
                ah = fmaf(rh[j], sW[5][i * DIM + j], ah);
            }
            outv[i] = zz[i] * hv[i] + (1.0f - zz[i]) * tanhf(ah);
        }
    } else {
        #pragma unroll
        for (int i = 0; i < DIM; ++i) outv[i] = hv[i];
    }
    if (iter == 0 && dep > 1) {
        #pragma unroll
        for (int i = 0; i < DIM; ++i) outv[i] = 0.0f;
    }
    #pragma unroll
    for (int i = 0; i < DIM; ++i) out[(size_t)node * DIM + i] = outv[i];
}

extern "C" void kernel_launch(void* const* d_in, const int* in_sizes, int n_in,
                              void* d_out, int out_size, void* d_ws, size_t ws_size,
                              hipStream_t stream) {
    const float* h_in  = (const float*)d_in[0];
    const int*   edges = (const int*)d_in[1];
    const int*   depth = (const int*)d_in[2];
    GruW gw;
    gw.Wz  = (const float*)d_in[3];  gw.bz  = (const float*)d_in[4];
    gw.Uz  = (const float*)d_in[5];  gw.buz = (const float*)d_in[6];
    gw.Wr  = (const float*)d_in[7];  gw.br  = (const float*)d_in[8];
    gw.Ur  = (const float*)d_in[9];  gw.bur = (const float*)d_in[10];
    gw.Wh  = (const float*)d_in[11]; gw.bh  = (const float*)d_in[12];
    gw.Uh  = (const float*)d_in[13]; gw.buh = (const float*)d_in[14];

    const int n  = in_sizes[0] / DIM;       // 500,000
    const int ne = in_sizes[1] / 2;         // 8,000,000
    const int* recv = edges;
    const int* send = edges + ne;

    const int NB = (n + BKT - 1) >> BKT_LOG;
    const size_t meta_words = (size_t)NPART * NBMAX + 8 + OVFCAP + D2WORDS;
    const size_t need = (size_t)n * 16 * sizeof(uint16_t) * 2            // h16a+h16b
                      + (size_t)NPART * NB * CAP * sizeof(uint32_t)      // bins
                      + meta_words * sizeof(uint32_t);

    const int BLK = 256;

    if (ws_size >= need && n <= (1 << 19) && NB <= NBMAX && out_size >= n * DIM) {
        uint16_t* h16a = (uint16_t*)d_ws;
        uint16_t* h16b = h16a + (size_t)n * 16;
        uint32_t* bins = (uint32_t*)(h16b + (size_t)n * 16);
        uint32_t* meta = bins + (size_t)NPART * NB * CAP;
        uint32_t* cnt    = meta;                             // NPART*NBMAX
        uint32_t* ovfc   = meta + (size_t)NPART * NBMAX;     // 8
        uint32_t* ovf    = ovfc + 8;                         // OVFCAP
        uint32_t* depth2 = ovf + OVFCAP;                     // D2WORDS

        const int bin_blocks  = (ne + EPW - 1) / EPW;
        const int node_blocks = (n + NTILE - 1) / NTILE;
        const int pack_blocks = (n + 4095) / 4096;
        const int cnt_tot = NPART * NBMAX + 1;
        const int cnt_blocks = (cnt_tot + 255) / 256;

        prep_kernel<<<pack_blocks + cnt_blocks, BLK, 0, stream>>>(
            depth, depth2, cnt, n, pack_blocks, cnt_tot);
        binit_kernel<<<bin_blocks + node_blocks, BLK, 0, stream>>>(
            recv, send, depth2, depth, h_in, h16a,
            cnt, ovfc, ovf, bins, ne, n, NB, bin_blocks);

        float* out32 = (float*)d_out;
        float* nullf = nullptr;
        uint16_t* nullh = nullptr;
        int n_ = n, NB_ = NB;

        // ---- iteration 0 (cooperative; fallback to plain on error) ----
        {
            void* args[] = { (void*)&bins, (void*)&cnt, (void*)&ovfc, (void*)&ovf,
                             (void*)&recv, (void*)&send, (void*)&depth,
                             (void*)&h16a, (void*)&h16b, (void*)&nullf,
                             (void*)&n_, (void*)&NB_, (void*)&gw };
            hipError_t err = hipLaunchCooperativeKernel(
                reinterpret_cast<const void*>(&scatgru_kernel<0, 1>),
                dim3(NB), dim3(BLK), args, 0, stream);
            if (err != hipSuccess) {
                scatgru_kernel<0, 0><<<NB, BLK, 0, stream>>>(
                    bins, cnt, ovfc, ovf, recv, send, depth,
                    h16a, h16b, nullptr, n, NB, gw);
            }
        }

        // ---- iteration 1 ----
        {
            void* args[] = { (void*)&bins, (void*)&cnt, (void*)&ovfc, (void*)&ovf,
                             (void*)&recv, (void*)&send, (void*)&depth,
                             (void*)&h16b, (void*)&nullh, (void*)&out32,
                             (void*)&n_, (void*)&NB_, (void*)&gw };
            hipError_t err = hipLaunchCooperativeKernel(
                reinterpret_cast<const void*>(&scatgru_kernel<1, 1>),
                dim3(NB), dim3(BLK), args, 0, stream);
            if (err != hipSuccess) {
                scatgru_kernel<1, 0><<<NB, BLK, 0, stream>>>(
                    bins, cnt, ovfc, ovf, recv, send, depth,
                    h16b, nullptr, out32, n, NB, gw);
            }
        }
    } else {
        // fallback: fp32 global-atomic pipeline, h in d_out, x in ws
        float* x    = (float*)d_ws;
        float* hbuf = (float*)d_out;
        const int nwork = ne * DIM;
        const int edge_blocks = (nwork + BLK - 1) / BLK;
        const int x_tot4 = (n * DIM) / 4;
        const int xz_blocks = (x_tot4 + BLK - 1) / BLK;
        const int nb2 = (n + BLK - 1) / BLK;

        init_mask32_kernel<<<nb2, BLK, 0, stream>>>(h_in, hbuf, depth, n);
        zero_buf_kernel<<<xz_blocks, BLK, 0, stream>>>((float4*)x, x_tot4);
        simple_scatter_kernel<<<edge_blocks, BLK, 0, stream>>>(recv, send, hbuf, x, ne);
        gru32_kernel<<<nb2, BLK, 0, stream>>>(x, hbuf, hbuf, depth, 0, n, gw);
        zero_buf_kernel<<<xz_blocks, BLK, 0, stream>>>((float4*)x, x_tot4);
        simple_scatter_kernel<<<edge_blocks, BLK, 0, stream>>>(recv, send, hbuf, x, ne);
        gru32_kernel<<<nb2, BLK, 0, stream>>>(x, hbuf, hbuf, depth, 1, n, gw);
    }
}

// Round 17
// 1687.981 us; speedup vs baseline: 2.0121x; 2.0121x over previous
//
#include <hip/hip_runtime.h>
#include <hip/hip_fp16.h>
#include <math.h>
#include <stdint.h>

#define DIM 10
#define NTILE 256
#define BKT_LOG 8
#define BKT 256                   // nodes per bucket == threads per WG
#define NBMAX 2048
#define EPW 2048                  // edges per WG in binning
#define KPT (EPW / 256)
#define NPART 8                   // send partitions (s>>16: 64K nodes = 2MB h16)
#define PSHIFT 16
#define CAP 448                   // slots per (p,b) cell: mean 288 + 9.4 sigma
#define OVFCAP 32768
#define D2WORDS 32768
#define XSTR 11                   // xl LDS stride (coprime with 32 banks)
#define SPIN_LIMIT 256            // relaxed-barrier timeout (perf-only)

// meta (u32): cnt[NPART*NBMAX] | ovfc[8] | bar[16] | ovf[OVFCAP] | depth2[D2WORDS]
// ws: h16a[n*16 u16] | h16b[n*16 u16] | bins[NPART*NB*CAP u32] | meta

struct GruW {
    const float *Wz, *bz, *Uz, *buz, *Wr, *br, *Ur, *bur, *Wh, *bh, *Uh, *buh;
};

__device__ __forceinline__ float2 cvt2(uint32_t u) {
    __half2 hh = *reinterpret_cast<__half2*>(&u);
    return __half22float2(hh);
}

__device__ __forceinline__ int d2get(const uint32_t* __restrict__ depth2, int node) {
    uint32_t w = depth2[(uint32_t)node >> 4];
    return (int)((w >> ((node & 15) * 2)) & 3u);
}

// ---------------------------------------------------------------------------
// prep: [0,pack) pack depth->2b | rest zero cnt + ovfc + bar
// ---------------------------------------------------------------------------
__global__ void prep_kernel(const int* __restrict__ depth,
                            uint32_t* __restrict__ depth2,
                            uint32_t* __restrict__ cnts,
                            int n, int pack_blocks, int cnt_tot)
{
    __shared__ int sd[4096];
    const int t = threadIdx.x;
    const int bid = blockIdx.x;
    if (bid < pack_blocks) {
        const int base = bid * 4096;
        for (int i = t; i < 4096; i += 256) {
            int g = base + i;
            sd[i] = (g < n) ? depth[g] : 3;
        }
        __syncthreads();
        int wb = (base >> 4) + t;
        if (wb * 16 < n) {
            uint32_t v = 0;
            #pragma unroll
            for (int j = 0; j < 16; ++j)
                v |= ((uint32_t)(sd[t * 16 + j] & 3)) << (2 * j);
            depth2[wb] = v;
        }
    } else {
        int i = (bid - pack_blocks) * 256 + t;
        if (i < cnt_tot) cnts[i] = 0;
    }
}

// ---------------------------------------------------------------------------
// binit: blocks [0,bin_blocks) bin edges into (p,b) cells; rest init h16a.
// word = s(19b) | rl(8b)<<19 | flag(useful@iter1)<<27
// ---------------------------------------------------------------------------
__global__ __launch_bounds__(256) void binit_kernel(
                           const int* __restrict__ recv,
                           const int* __restrict__ send,
                           const uint32_t* __restrict__ depth2,
                           const int* __restrict__ depth,
                           const float* __restrict__ h_in,
                           uint16_t* __restrict__ h16a,
                           uint32_t* __restrict__ cnt,
                           uint32_t* __restrict__ ovfc,
                           uint32_t* __restrict__ ovf,
                           uint32_t* __restrict__ bins,
                           int ne, int n, int NB, int bin_blocks)
{
    __shared__ float sh[NTILE * 11];
    const int t = threadIdx.x;
    const int bid = blockIdx.x;

    if (bid < bin_blocks) {
        const int base = bid * EPW;
        int rA[KPT], sA[KPT];
        #pragma unroll
        for (int k = 0; k < KPT; ++k) {
            int e = base + k * 256 + t;
            if (e < ne) { rA[k] = recv[e]; sA[k] = send[e]; }
            else        { rA[k] = -1;      sA[k] = 0;       }
        }
        int drA[KPT], dsA[KPT];
        #pragma unroll
        for (int k = 0; k < KPT; ++k) {
            if (rA[k] >= 0) { drA[k] = d2get(depth2, rA[k]); dsA[k] = d2get(depth2, sA[k]); }
            else            { drA[k] = 3;                    dsA[k] = 3;                    }
        }
        #pragma unroll
        for (int k = 0; k < KPT; ++k) {
            if (rA[k] >= 0 && drA[k] <= 2 && dsA[k] <= 2) {
                int r = rA[k], s = sA[k];
                bool f1 = (drA[k] <= 1) && (dsA[k] <= 1);
                uint32_t w = (uint32_t)s | ((uint32_t)(r & (BKT - 1)) << 19)
                           | (f1 ? (1u << 27) : 0u);
                int cell = (s >> PSHIFT) * NB + (r >> BKT_LOG);
                uint32_t pos = atomicAdd(&cnt[cell], 1u);
                if (pos < CAP) bins[(size_t)cell * CAP + pos] = w;
                else { uint32_t oi = atomicAdd(ovfc, 1u);
                       if (oi < OVFCAP) ovf[oi] = (uint32_t)(base + k * 256 + t); }
            }
        }
    } else {
        // init: h16a[node] = fp16( (depth<=2) ? h_in[node] : 0 ), pads 0
        const int base = (bid - bin_blocks) * NTILE;
        const long gbase = (long)base * DIM;
        const long glim  = (long)n * DIM;
        for (int idx = t; idx < NTILE * DIM; idx += NTILE) {
            long g = gbase + idx;
            float v = (g < glim) ? h_in[g] : 0.0f;
            sh[(idx / DIM) * 11 + (idx % DIM)] = v;
        }
        __syncthreads();
        const int node = base + t;
        if (node < n && depth[node] > 2) {
            #pragma unroll
            for (int c = 0; c < DIM; ++c) sh[t * 11 + c] = 0.0f;
        }
        __syncthreads();
        uint32_t* o16 = reinterpret_cast<uint32_t*>(h16a);
        const long o16base = (long)base * 8;
        const long o16lim  = (long)n * 8;
        for (int idx = t; idx < NTILE * 8; idx += NTILE) {
            long g = o16base + idx;
            if (g < o16lim) {
                int nl = idx / 8, c2 = idx % 8;
                uint32_t w = 0;
                if (c2 < 5) {
                    __half2 hh = __floats2half2_rn(sh[nl * 11 + 2 * c2],
                                                   sh[nl * 11 + 2 * c2 + 1]);
                    w = *reinterpret_cast<uint32_t*>(&hh);
                }
                o16[g] = w;
            }
        }
    }
}

// ---------------------------------------------------------------------------
// fused scatter + GRU with partition phasing via RELAXED barrier:
// no fences, no L2 flush (phasing is perf-only; h16 is read-only here and
// each WG owns its LDS slice). Timeout-bounded spin -> can never deadlock;
// timeout just degrades cache locality. COOP launch guarantees co-residency.
// ---------------------------------------------------------------------------
template<int ITER, int COOP>
__global__ __launch_bounds__(256, 8) void scatgru_kernel(
                            const uint32_t* __restrict__ bins,
                            const uint32_t* __restrict__ cnt,
                            const uint32_t* __restrict__ ovfc,
                            const uint32_t* __restrict__ ovf,
                            const int* __restrict__ recv,
                            const int* __restrict__ send,
                            const int* __restrict__ depth,
                            const uint16_t* __restrict__ hcur,  // stride 16 halfs
                            uint16_t* __restrict__ hnext,       // ITER==0 out
                            float* __restrict__ out32,          // ITER==1 out
                            uint32_t* bar,                      // bar + ITER*8
                            int n, int NB, GruW w)
{
    __shared__ float xl[BKT * XSTR];     // 11264 B
    __shared__ float sW[6][100];
    __shared__ float sb[3][10];

    const int t = threadIdx.x;
    if (t < 100) {
        sW[0][t] = w.Wz[t]; sW[1][t] = w.Uz[t];
        sW[2][t] = w.Wr[t]; sW[3][t] = w.Ur[t];
        sW[4][t] = w.Wh[t]; sW[5][t] = w.Uh[t];
    }
    if (t < 10) {
        sb[0][t] = w.bz[t] + w.buz[t];
        sb[1][t] = w.br[t] + w.bur[t];
        sb[2][t] = w.bh[t] + w.buh[t];
    }
    for (int i = t; i < BKT * XSTR; i += 256) xl[i] = 0.0f;
    __syncthreads();

    const int b = blockIdx.x;
    const int n0 = b << BKT_LOG;
    const int nb = min(BKT, n - n0);

    // phase 1: partition-phased gather + LDS accumulate
    for (int p = 0; p < NPART; ++p) {
        const int cell = p * NB + b;
        const size_t base = (size_t)cell * CAP;
        const int tot = (int)min(cnt[cell], (uint32_t)CAP);
        for (int i = t; i < tot; i += 256) {
            uint32_t ww = bins[base + i];
            if (ITER == 1 && !((ww >> 27) & 1u)) continue;
            size_t s = (size_t)(ww & 0x7FFFFu);
            uint4 q = *reinterpret_cast<const uint4*>(hcur + s * 16);
            uint32_t e8 = *reinterpret_cast<const uint32_t*>(hcur + s * 16 + 8);
            float2 f0 = cvt2(q.x), f1 = cvt2(q.y), f2 = cvt2(q.z), f3 = cvt2(q.w);
            float2 f4 = cvt2(e8);
            float* xr = xl + ((ww >> 19) & (BKT - 1)) * XSTR;
            atomicAdd(xr + 0, f0.x); atomicAdd(xr + 1, f0.y);
            atomicAdd(xr + 2, f1.x); atomicAdd(xr + 3, f1.y);
            atomicAdd(xr + 4, f2.x); atomicAdd(xr + 5, f2.y);
            atomicAdd(xr + 6, f3.x); atomicAdd(xr + 7, f3.y);
            atomicAdd(xr + 8, f4.x); atomicAdd(xr + 9, f4.y);
        }
        if (COOP && p + 1 < NPART) {
            // relaxed, fence-free, timeout-bounded phase barrier (perf-only)
            __syncthreads();
            if (t == 0) {
                atomicAdd(&bar[p], 1u);
                int spins = 0;
                while (__hip_atomic_load(&bar[p], __ATOMIC_RELAXED,
                                         __HIP_MEMORY_SCOPE_AGENT) < (uint32_t)gridDim.x
                       && spins < SPIN_LIMIT) {
                    ++spins;
                    __builtin_amdgcn_s_sleep(8);
                }
            }
            __syncthreads();
        }
    }

    // phase 2: rare overflow edges for this bucket
    {
        const uint32_t cntv = min(*ovfc, (uint32_t)OVFCAP);
        for (uint32_t i = t; i < cntv; i += 256) {
            int e = (int)ovf[i];
            int r = recv[e];
            if ((r >> BKT_LOG) != b) continue;
            int s = send[e];
            if (ITER == 1 && (depth[r] > 1 || depth[s] > 1)) continue;
            uint4 q = *reinterpret_cast<const uint4*>(hcur + (size_t)s * 16);
            uint32_t e8v = *reinterpret_cast<const uint32_t*>(hcur + (size_t)s * 16 + 8);
            float2 f0 = cvt2(q.x), f1 = cvt2(q.y), f2 = cvt2(q.z), f3 = cvt2(q.w);
            float2 f4 = cvt2(e8v);
            float* xr = xl + (r & (BKT - 1)) * XSTR;
            atomicAdd(xr + 0, f0.x); atomicAdd(xr + 1, f0.y);
            atomicAdd(xr + 2, f1.x); atomicAdd(xr + 3, f1.y);
            atomicAdd(xr + 4, f2.x); atomicAdd(xr + 5, f2.y);
            atomicAdd(xr + 6, f3.x); atomicAdd(xr + 7, f3.y);
            atomicAdd(xr + 8, f4.x); atomicAdd(xr + 9, f4.y);
        }
    }
    __syncthreads();

    // phase 3: GRU for node n0+t (register-dieted)
    if (t < nb) {
        const int node = n0 + t;
        const int dep = depth[node];
        const bool active = (dep + ITER) <= 2;

        float hv[DIM];
        {
            const uint16_t* hp = hcur + (size_t)node * 16;
            uint4 q = *reinterpret_cast<const uint4*>(hp);
            uint32_t e8v = *reinterpret_cast<const uint32_t*>(hp + 8);
            float2 f0 = cvt2(q.x), f1 = cvt2(q.y), f2 = cvt2(q.z), f3 = cvt2(q.w);
            float2 f4 = cvt2(e8v);
            hv[0] = f0.x; hv[1] = f0.y; hv[2] = f1.x; hv[3] = f1.y;
            hv[4] = f2.x; hv[5] = f2.y; hv[6] = f3.x; hv[7] = f3.y;
            hv[8] = f4.x; hv[9] = f4.y;
        }
        float xv[DIM];
        #pragma unroll
        for (int j = 0; j < DIM; ++j) xv[j] = xl[t * XSTR + j];

        float zz[DIM];
        if (active) {
            #pragma unroll
            for (int i = 0; i < DIM; ++i) {
                float az = sb[0][i];
                float ar = sb[1][i];
                #pragma unroll
                for (int j = 0; j < DIM; ++j) {
                    az = fmaf(xv[j], sW[0][i * DIM + j], az);
                    az = fmaf(hv[j], sW[1][i * DIM + j], az);
                    ar = fmaf(xv[j], sW[2][i * DIM + j], ar);
                    ar = fmaf(hv[j], sW[3][i * DIM + j], ar);
                }
                zz[i] = 1.0f / (1.0f + __expf(-az));
                xl[t * XSTR + i] = (1.0f / (1.0f + __expf(-ar))) * hv[i];  // rh
            }
        }

        if (ITER == 0) {
            uint32_t packed[5];
            float prev = 0.0f;
            #pragma unroll
            for (int i = 0; i < DIM; ++i) {
                float o;
                if (active) {
                    float ah = sb[2][i];
                    #pragma unroll
                    for (int j = 0; j < DIM; ++j) {
                        ah = fmaf(xv[j], sW[4][i * DIM + j], ah);
                        ah = fmaf(xl[t * XSTR + j], sW[5][i * DIM + j], ah);
                    }
                    o = zz[i] * hv[i] + (1.0f - zz[i]) * tanhf(ah);
                } else {
                    o = hv[i];
                }
                if (dep > 1) o = 0.0f;     // fold iter-1 mask
                if (i & 1) {
                    __half2 hh = __floats2half2_rn(prev, o);
                    packed[i >> 1] = *reinterpret_cast<uint32_t*>(&hh);
                } else prev = o;
            }
            uint4 o0 = make_uint4(packed[0], packed[1], packed[2], packed[3]);
            uint4 o1 = make_uint4(packed[4], 0u, 0u, 0u);
            *reinterpret_cast<uint4*>(hnext + (size_t)node * 16)     = o0;
            *reinterpret_cast<uint4*>(hnext + (size_t)node * 16 + 8) = o1;
        } else {
            float2* op = reinterpret_cast<float2*>(out32 + (size_t)node * DIM);
            float prev = 0.0f;
            #pragma unroll
            for (int i = 0; i < DIM; ++i) {
                float o;
                if (active) {
                    float ah = sb[2][i];
                    #pragma unroll
                    for (int j = 0; j < DIM; ++j) {
                        ah = fmaf(xv[j], sW[4][i * DIM + j], ah);
                        ah = fmaf(xl[t * XSTR + j], sW[5][i * DIM + j], ah);
                    }
                    o = zz[i] * hv[i] + (1.0f - zz[i]) * tanhf(ah);
                } else {
                    o = hv[i];
                }
                if (i & 1) op[i >> 1] = make_float2(prev, o);
                else prev = o;
            }
        }
    }
}

// ---------------------------------------------------------------------------
// fallback path (ws too small / n too large): fp32 global-atomic pipeline
// ---------------------------------------------------------------------------
__global__ void init_mask32_kernel(const float* __restrict__ hsrc,
                                   float* __restrict__ hdst,
                                   const int* __restrict__ depth, int n)
{
    int node = blockIdx.x * blockDim.x + threadIdx.x;
    if (node >= n) return;
    bool act = depth[node] <= 2;
    const float* s = hsrc + (size_t)node * DIM;
    float* d = hdst + (size_t)node * DIM;
    #pragma unroll
    for (int c = 0; c < DIM; ++c) d[c] = act ? s[c] : 0.0f;
}

__global__ void simple_scatter_kernel(const int* __restrict__ recv,
                                      const int* __restrict__ send,
                                      const float* __restrict__ hm,
                                      float* __restrict__ x, int ne)
{
    const int tid = blockIdx.x * blockDim.x + threadIdx.x;
    const int e = tid / DIM;
    if (e >= ne) return;
    const int c = tid - e * DIM;
    const int s = send[e];
    const float v = hm[(size_t)s * DIM + c];
    if (v != 0.0f) {
        const int r = recv[e];
        unsafeAtomicAdd(x + (size_t)r * DIM + c, v);
    }
}

__global__ void zero_buf_kernel(float4* __restrict__ p, int tot4) {
    int i = blockIdx.x * blockDim.x + threadIdx.x;
    if (i < tot4) p[i] = make_float4(0.0f, 0.0f, 0.0f, 0.0f);
}

__global__ void gru32_kernel(const float* __restrict__ x,
                             const float* __restrict__ h,
                             float* __restrict__ out,
                             const int* __restrict__ depth, int iter, int n, GruW w)
{
    __shared__ float sW[6][100];
    __shared__ float sb[3][10];
    const int t = threadIdx.x;
    if (t < 100) {
        sW[0][t] = w.Wz[t]; sW[1][t] = w.Uz[t];
        sW[2][t] = w.Wr[t]; sW[3][t] = w.Ur[t];
        sW[4][t] = w.Wh[t]; sW[5][t] = w.Uh[t];
    }
    if (t < 10) {
        sb[0][t] = w.bz[t] + w.buz[t];
        sb[1][t] = w.br[t] + w.bur[t];
        sb[2][t] = w.bh[t] + w.buh[t];
    }
    __syncthreads();

    int node = blockIdx.x * blockDim.x + t;
    if (node >= n) return;
    const int dep = depth[node];
    const bool active = dep + iter <= 2;
    float xv[DIM], hv[DIM], outv[DIM];
    #pragma unroll
    for (int j = 0; j < DIM; ++j) {
        xv[j] = x[(size_t)node * DIM + j];
        hv[j] = h[(size_t)node * DIM + j];
    }
    if (active) {
        float zz[DIM], rh[DIM];
        #pragma unroll
        for (int i = 0; i < DIM; ++i) {
            float az = sb[0][i], ar = sb[1][i];
            #pragma unroll
            for (int j = 0; j < DIM; ++j) {
                az = fmaf(xv[j], sW[0][i * DIM + j], az);
                az = fmaf(hv[j], sW[1][i * DIM + j], az);
                ar = fmaf(xv[j], sW[2][i * DIM + j], ar);
                ar = fmaf(hv[j], sW[3][i * DIM + j], ar);
            }
            zz[i] = 1.0f / (1.0f + __expf(-az));
            rh[i] = (1.0f / (1.0f + __expf(-ar))) * hv[i];
        }
        #pragma unroll
        for (int i = 0; i < DIM; ++i) {
            float ah = sb[2][i];
            #pragma unroll
            for (int j = 0; j < DIM; ++j) {
                ah = fmaf(xv[j], sW[4][i * DIM + j], ah);
                ah = fmaf(rh[j], sW[5][i * DIM + j], ah);
            }
            outv[i] = zz[i] * hv[i] + (1.0f - zz[i]) * tanhf(ah);
        }
    } else {
        #pragma unroll
        for (int i = 0; i < DIM; ++i) outv[i] = hv[i];
    }
    if (iter == 0 && dep > 1) {
        #pragma unroll
        for (int i = 0; i < DIM; ++i) outv[i] = 0.0f;
    }
    #pragma unroll
    for (int i = 0; i < DIM; ++i) out[(size_t)node * DIM + i] = outv[i];
}

extern "C" void kernel_launch(void* const* d_in, const int* in_sizes, int n_in,
                              void* d_out, int out_size, void* d_ws, size_t ws_size,
                              hipStream_t stream) {
    const float* h_in  = (const float*)d_in[0];
    const int*   edges = (const int*)d_in[1];
    const int*   depth = (const int*)d_in[2];
    GruW gw;
    gw.Wz  = (const float*)d_in[3];  gw.bz  = (const float*)d_in[4];
    gw.Uz  = (const float*)d_in[5];  gw.buz = (const float*)d_in[6];
    gw.Wr  = (const float*)d_in[7];  gw.br  = (const float*)d_in[8];
    gw.Ur  = (const float*)d_in[9];  gw.bur = (const float*)d_in[10];
    gw.Wh  = (const float*)d_in[11]; gw.bh  = (const float*)d_in[12];
    gw.Uh  = (const float*)d_in[13]; gw.buh = (const float*)d_in[14];

    const int n  = in_sizes[0] / DIM;       // 500,000
    const int ne = in_sizes[1] / 2;         // 8,000,000
    const int* recv = edges;
    const int* send = edges + ne;

    const int NB = (n + BKT - 1) >> BKT_LOG;
    const size_t meta_words = (size_t)NPART * NBMAX + 8 + 16 + OVFCAP + D2WORDS;
    const size_t need = (size_t)n * 16 * sizeof(uint16_t) * 2            // h16a+h16b
                      + (size_t)NPART * NB * CAP * sizeof(uint32_t)      // bins
                      + meta_words * sizeof(uint32_t);

    const int BLK = 256;

    if (ws_size >= need && n <= (1 << 19) && NB <= NBMAX && out_size >= n * DIM) {
        uint16_t* h16a = (uint16_t*)d_ws;
        uint16_t* h16b = h16a + (size_t)n * 16;
        uint32_t* bins = (uint32_t*)(h16b + (size_t)n * 16);
        uint32_t* meta = bins + (size_t)NPART * NB * CAP;
        uint32_t* cnt    = meta;                             // NPART*NBMAX
        uint32_t* ovfc   = meta + (size_t)NPART * NBMAX;     // 8
        uint32_t* bar    = ovfc + 8;                         // 16 (8 per iter)
        uint32_t* ovf    = bar + 16;                         // OVFCAP
        uint32_t* depth2 = ovf + OVFCAP;                     // D2WORDS

        const int bin_blocks  = (ne + EPW - 1) / EPW;
        const int node_blocks = (n + NTILE - 1) / NTILE;
        const int pack_blocks = (n + 4095) / 4096;
        const int cnt_tot = NPART * NBMAX + 8 + 16;          // cnt + ovfc + bar
        const int cnt_blocks = (cnt_tot + 255) / 256;

        prep_kernel<<<pack_blocks + cnt_blocks, BLK, 0, stream>>>(
            depth, depth2, cnt, n, pack_blocks, cnt_tot);
        binit_kernel<<<bin_blocks + node_blocks, BLK, 0, stream>>>(
            recv, send, depth2, depth, h_in, h16a,
            cnt, ovfc, ovf, bins, ne, n, NB, bin_blocks);

        float* out32 = (float*)d_out;
        float* nullf = nullptr;
        uint16_t* nullh = nullptr;
        int n_ = n, NB_ = NB;
        uint32_t* bar0 = bar;
        uint32_t* bar1 = bar + 8;

        // ---- iteration 0 (cooperative for co-residency; relaxed barrier) ----
        {
            void* args[] = { (void*)&bins, (void*)&cnt, (void*)&ovfc, (void*)&ovf,
                             (void*)&recv, (void*)&send, (void*)&depth,
                             (void*)&h16a, (void*)&h16b, (void*)&nullf,
                             (void*)&bar0, (void*)&n_, (void*)&NB_, (void*)&gw };
            hipError_t err = hipLaunchCooperativeKernel(
                reinterpret_cast<const void*>(&scatgru_kernel<0, 1>),
                dim3(NB), dim3(BLK), args, 0, stream);
            if (err != hipSuccess) {
                scatgru_kernel<0, 0><<<NB, BLK, 0, stream>>>(
                    bins, cnt, ovfc, ovf, recv, send, depth,
                    h16a, h16b, nullptr, bar0, n, NB, gw);
            }
        }

        // ---- iteration 1 ----
        {
            void* args[] = { (void*)&bins, (void*)&cnt, (void*)&ovfc, (void*)&ovf,
                             (void*)&recv, (void*)&send, (void*)&depth,
                             (void*)&h16b, (void*)&nullh, (void*)&out32,
                             (void*)&bar1, (void*)&n_, (void*)&NB_, (void*)&gw };
            hipError_t err = hipLaunchCooperativeKernel(
                reinterpret_cast<const void*>(&scatgru_kernel<1, 1>),
                dim3(NB), dim3(BLK), args, 0, stream);
            if (err != hipSuccess) {
                scatgru_kernel<1, 0><<<NB, BLK, 0, stream>>>(
                    bins, cnt, ovfc, ovf, recv, send, depth,
                    h16b, nullptr, out32, bar1, n, NB, gw);
            }
        }
    } else {
        // fallback: fp32 global-atomic pipeline, h in d_out, x in ws
        float* x    = (float*)d_ws;
        float* hbuf = (float*)d_out;
        const int nwork = ne * DIM;
        const int edge_blocks = (nwork + BLK - 1) / BLK;
        const int x_tot4 = (n * DIM) / 4;
        const int xz_blocks = (x_tot4 + BLK - 1) / BLK;
        const int nb2 = (n + BLK - 1) / BLK;

        init_mask32_kernel<<<nb2, BLK, 0, stream>>>(h_in, hbuf, depth, n);
        zero_buf_kernel<<<xz_blocks, BLK, 0, stream>>>((float4*)x, x_tot4);
        simple_scatter_kernel<<<edge_blocks, BLK, 0, stream>>>(recv, send, hbuf, x, ne);
        gru32_kernel<<<nb2, BLK, 0, stream>>>(x, hbuf, hbuf, depth, 0, n, gw);
        zero_buf_kernel<<<xz_blocks, BLK, 0, stream>>>((float4*)x, x_tot4);
        simple_scatter_kernel<<<edge_blocks, BLK, 0, stream>>>(recv, send, hbuf, x, ne);
        gru32_kernel<<<nb2, BLK, 0, stream>>>(x, hbuf, hbuf, depth, 1, n, gw);
    }
}